// Round 27
// baseline (366.131 us; speedup 1.0000x reference)
//
#include <hip/hip_runtime.h>
#include <math.h>

#define HID 256
#define PI_F 3.14159265358979323846f
typedef unsigned long long ull;
typedef float f4v __attribute__((ext_vector_type(4)));

struct F3 { float x, y, z; };

// ---- LOCKED NUMERICS (passing recipe, R14): clean dist (no FMA, numpy order,
// CR sqrt) + contracted crosses (fma(a.y,b.z,-(a.z*b.y))) + clean dots ----
__device__ __forceinline__ F3 crossc(F3 a, F3 b) {
    F3 r;
    float t1 = a.z * b.y;
    r.x = __builtin_fmaf(a.y, b.z, -t1);
    float t2 = a.x * b.z;
    r.y = __builtin_fmaf(a.z, b.x, -t2);
    float t3 = a.y * b.x;
    r.z = __builtin_fmaf(a.x, b.y, -t3);
    return r;
}
__device__ __forceinline__ float dotf(F3 a, F3 b) {
#pragma clang fp contract(off)
    float px = a.x * b.x;
    float py = a.y * b.y;
    float pz = a.z * b.z;
    return (px + py) + pz;
}
__device__ __forceinline__ float sqrt_cr(float ss) {
    return (float)sqrt((double)ss);
}
__device__ __forceinline__ float safe_atan2(float b, float a) {
    float aa = (a == 0.f && b == 0.f) ? 1.f : a;
    return atan2f(b, aa);
}
__device__ __forceinline__ F3 loadp(const float* __restrict__ pos, int n) {
    F3 r;
    r.x = pos[3 * n + 0];
    r.y = pos[3 * n + 1];
    r.z = pos[3 * n + 2];
    return r;
}
__device__ __forceinline__ F3 loadv(const float* __restrict__ vecs, int e) {
    F3 r;
    r.x = vecs[3 * (size_t)e + 0];
    r.y = vecs[3 * (size_t)e + 1];
    r.z = vecs[3 * (size_t)e + 2];
    return r;
}
__device__ __forceinline__ F3 subv(F3 a, F3 b) {
#pragma clang fp contract(off)
    F3 r;
    r.x = a.x - b.x;
    r.y = a.y - b.y;
    r.z = a.z - b.z;
    return r;
}
__device__ __forceinline__ ull umin64(ull a, ull b) { return a < b ? a : b; }
__device__ __forceinline__ ull umax64(ull a, ull b) { return a > b ? a : b; }

// two-slot lex-min insert, slots interleaved (s[0]=min, s[1]=2nd-min).
// Stale-safe filter: hi words monotone non-increasing; stale >= current.
// Invariant: every key not ending in s[0] is offered to s[1] at least once.
__device__ __forceinline__ void insert2(ull* __restrict__ s, unsigned db, ull key) {
    unsigned hi2 = ((const unsigned*)s)[3];
    if (db > hi2) return;
    unsigned hi1 = ((const unsigned*)s)[1];
    if (db <= hi1) {
        ull ret = atomicMin(&s[0], key);
        ull loser = umax64(ret, key);
        if (loser != ~0ull) atomicMin(&s[1], loser);
    } else {
        atomicMin(&s[1], key);
    }
}

// ---------------- pass1 chunk: dist+vecs (locked) + snapshot-filtered top-2 ----------------
// thrA/thrB are CLEAN (written only between chunks) -> L2-cacheable; a skip on
// db > thr is safe because thr >= current slot2-hi (monotone + stream order).
// vecs/dist stores are NONTEMPORAL: 51MB of streaming writes that would evict
// the hot slot/thr lines from L2 (they're only re-read a full sweep later).
__global__ void k_pass1(const int* __restrict__ ei, const int* __restrict__ ej,
                        const float* __restrict__ pos, float* __restrict__ dist,
                        float* __restrict__ vecs,
                        ull* __restrict__ slotsA, ull* __restrict__ slotsB,
                        const unsigned* __restrict__ thrA, const unsigned* __restrict__ thrB,
                        int e0, int e1) {
#pragma clang fp contract(off)
    int e = e0 + blockIdx.x * blockDim.x + threadIdx.x;
    if (e >= e1) return;
    int ii = ei[e], jj = ej[e];
    F3 v = subv(loadp(pos, jj), loadp(pos, ii));
    __builtin_nontemporal_store(v.x, &vecs[3 * (size_t)e + 0]);
    __builtin_nontemporal_store(v.y, &vecs[3 * (size_t)e + 1]);
    __builtin_nontemporal_store(v.z, &vecs[3 * (size_t)e + 2]);
    float sx = v.x * v.x;
    float sy = v.y * v.y;
    float sz = v.z * v.z;
    float ss = (sx + sy) + sz;
    float d = (ss == 0.f) ? 0.f : sqrt_cr(ss);
    __builtin_nontemporal_store(d, &dist[e]);
    unsigned db = __float_as_uint(d);
    ull key = ((ull)db << 32) | (unsigned)e;
    if (db <= thrA[ii]) insert2(&slotsA[2 * (size_t)ii], db, key);
    if (db <= thrB[jj]) insert2(&slotsB[2 * (size_t)jj], db, key);
}

// ---------------- snapshot: publish current 2nd-min dist-bits as clean thresholds ----------------
__global__ void k_snapshot(const ull* __restrict__ slotsA, const ull* __restrict__ slotsB,
                           unsigned* __restrict__ thrA, unsigned* __restrict__ thrB, int N) {
    int n = blockIdx.x * blockDim.x + threadIdx.x;
    if (n >= N) return;
    thrA[n] = (unsigned)(slotsA[2 * (size_t)n + 1] >> 32);
    thrB[n] = (unsigned)(slotsB[2 * (size_t)n + 1] >> 32);
}

// ---------------- prep: a0/a1 from top-2 + PAIRED node records (via vecs) ----------------
// in0 = vecs[a0] (bitwise == subv(pos[ej[a0]],pos[ei[a0]]) stored by pass1).
// argmin1 = lex-min( (bits(d0+8), a0), slot2 ) — bit-exact vs ref's dist+8 marking.
__global__ void k_prep(const ull* __restrict__ slotsA, const ull* __restrict__ slotsB,
                       const int* __restrict__ ei, const int* __restrict__ ej,
                       const float* __restrict__ vecs,
                       float4* __restrict__ nodeI, float4* __restrict__ nodeJ,
                       int* __restrict__ a0i, int* __restrict__ a0j,
                       unsigned* __restrict__ flags, int N) {
#pragma clang fp contract(off)
    int n = blockIdx.x * blockDim.x + threadIdx.x;
    if (n >= N) return;

    // A side
    ull k1 = slotsA[2 * (size_t)n];
    int a0, a1;
    if (k1 == ~0ull) {
        a0 = 0; a1 = 0;
        atomicOr(&flags[0], 1u);
    } else {
        a0 = (int)(k1 & 0xffffffffu);
        float d0 = __uint_as_float((unsigned)(k1 >> 32));
        ull mkey = ((ull)__float_as_uint(d0 + 8.0f) << 32) | (unsigned)a0;
        ull k2 = slotsA[2 * (size_t)n + 1];
        if (k2 == ~0ull) a1 = a0;                       // 1-edge segment
        else a1 = (mkey < k2) ? a0 : (int)(k2 & 0xffffffffu);
    }
    a0i[n] = a0;
    F3 in0 = loadv(vecs, a0);
    int n0 = ej[a0];
    F3 in1 = loadv(vecs, a1);
    nodeI[2 * (size_t)n]     = make_float4(in0.x, in0.y, in0.z, __int_as_float(n0));
    nodeI[2 * (size_t)n + 1] = make_float4(in1.x, in1.y, in1.z, 0.f);

    // B side
    ull q1 = slotsB[2 * (size_t)n];
    int b0, b1;
    if (q1 == ~0ull) {
        b0 = 0; b1 = 0;
        atomicOr(&flags[1], 1u);
    } else {
        b0 = (int)(q1 & 0xffffffffu);
        float d0 = __uint_as_float((unsigned)(q1 >> 32));
        ull mkey = ((ull)__float_as_uint(d0 + 8.0f) << 32) | (unsigned)b0;
        ull q2 = slotsB[2 * (size_t)n + 1];
        if (q2 == ~0ull) b1 = b0;
        else b1 = (mkey < q2) ? b0 : (int)(q2 & 0xffffffffu);
    }
    a0j[n] = b0;
    F3 w0 = loadv(vecs, b0);
    int m0 = ei[b0];
    F3 w1 = loadv(vecs, b1);
    nodeJ[2 * (size_t)n]     = make_float4(w0.x, w0.y, w0.z, __int_as_float(m0));
    nodeJ[2 * (size_t)n + 1] = make_float4(w1.x, w1.y, w1.z, 0.f);
}

// ---------------- fix: exact edge-0 marking when some segment is empty ----------------
// (never fires on this data; exact ref semantics if it does)
__global__ void k_fix(const unsigned* __restrict__ flags,
                      const int* __restrict__ ei, const int* __restrict__ ej,
                      const float* __restrict__ dist,
                      const int* __restrict__ a0i, const int* __restrict__ a0j,
                      const float* __restrict__ vecs,
                      float4* __restrict__ nodeI, float4* __restrict__ nodeJ, int E) {
#pragma clang fp contract(off)
    __shared__ ull smin[256];
    int side = blockIdx.x;          // 0 = A, 1 = B
    if (flags[side] == 0u) return;
    const int* seg = (side == 0) ? ei : ej;
    int s = seg[0];
    int marked = (side == 0) ? a0i[s] : a0j[s];
    ull local = ~0ull;
    for (int e = threadIdx.x; e < E; e += 256) {
        if (seg[e] != s) continue;
        float d = dist[e];
        float dm = (e == marked || e == 0) ? (d + 8.0f) : d;
        ull key = ((ull)__float_as_uint(dm) << 32) | (unsigned)e;
        local = umin64(local, key);
    }
    smin[threadIdx.x] = local;
    __syncthreads();
    for (int w = 128; w > 0; w >>= 1) {
        if (threadIdx.x < w) smin[threadIdx.x] = umin64(smin[threadIdx.x], smin[threadIdx.x + w]);
        __syncthreads();
    }
    if (threadIdx.x == 0) {
        int a1 = (smin[0] == ~0ull) ? 0 : (int)(smin[0] & 0xffffffffu);
        F3 v = loadv(vecs, a1);
        if (side == 0) nodeI[2 * (size_t)s + 1] = make_float4(v.x, v.y, v.z, 0.f);
        else           nodeJ[2 * (size_t)s + 1] = make_float4(v.x, v.y, v.z, 0.f);
    }
}

// ---------------- angles: streaming vecs + 2 paired-line gathers ----------------
__global__ void k_angles(const int* __restrict__ ei, const int* __restrict__ ej,
                         const float* __restrict__ vecs, const float* __restrict__ dist,
                         const float4* __restrict__ nodeI, const float4* __restrict__ nodeJ,
                         float* __restrict__ theta, float* __restrict__ phi,
                         float* __restrict__ tau, int E) {
    int e = blockIdx.x * blockDim.x + threadIdx.x;
    if (e >= E) return;
    int ii = ei[e], jj = ej[e];

    float4 A0 = nodeI[2 * (size_t)ii];
    float4 A1 = nodeI[2 * (size_t)ii + 1];
    float4 B0 = nodeJ[2 * (size_t)jj];
    float4 B1 = nodeJ[2 * (size_t)jj + 1];
    int n0 = __float_as_int(A0.w);
    int m0 = __float_as_int(B0.w);

    F3 in0; in0.x = A0.x; in0.y = A0.y; in0.z = A0.z;
    F3 in1; in1.x = A1.x; in1.y = A1.y; in1.z = A1.z;
    F3 w0;  w0.x = B0.x;  w0.y = B0.y;  w0.z = B0.z;
    F3 w1;  w1.x = B1.x;  w1.y = B1.y;  w1.z = B1.z;

    F3 iref = (n0 == jj) ? in1 : in0;
    F3 jref = (m0 == ii) ? w1 : w0;

    // p read STREAMING from vecs (bitwise == subv(pos[jj],pos[ii]) in pass1)
    F3 p = loadv(vecs, e);
    F3 mp;
    mp.x = -p.x; mp.y = -p.y; mp.z = -p.z;

    // theta
    float a = dotf(mp, in0);
    F3 c1 = crossc(mp, in0);
    float ssb = dotf(c1, c1);
    float b = (ssb == 0.f) ? 0.f : sqrt_cr(ssb);
    float th = safe_atan2(b, a);
    if (th < 0.f) th += PI_F;

    float dji = dist[e];

    // phi
    F3 pl2 = crossc(mp, in1);
    a = dotf(c1, pl2);
    F3 cc = crossc(c1, pl2);
    b = dotf(cc, p) / dji;
    float ph = safe_atan2(b, a);
    if (ph < 0.f) ph += PI_F;

    // tau
    F3 t1 = crossc(p, jref);
    F3 t2 = crossc(p, iref);
    a = dotf(t1, t2);
    cc = crossc(t1, t2);
    b = dotf(cc, p) / dji;
    float ta = safe_atan2(b, a);
    if (ta < 0.f) ta += PI_F;

    // outputs never re-read: nontemporal (keep L2 for node-record gathers)
    __builtin_nontemporal_store(th, &theta[e]);
    __builtin_nontemporal_store(ph, &phi[e]);
    __builtin_nontemporal_store(ta, &tau[e]);
}

// ---------------- embedding + swish (runs LAST: overwrites scratch) ----------------
__global__ void k_embed(const int* __restrict__ x, const float* __restrict__ w,
                        float* __restrict__ h, int total4) {
    int t = blockIdx.x * blockDim.x + threadIdx.x;
    if (t >= total4) return;
    int n = t >> 6;
    int c = t & 63;
    int row = x[n];
    float4 v = *reinterpret_cast<const float4*>(w + (size_t)row * HID + c * 4);
    f4v o;
    o.x = v.x / (1.f + expf(-v.x));
    o.y = v.y / (1.f + expf(-v.y));
    o.z = v.z / (1.f + expf(-v.z));
    o.w = v.w / (1.f + expf(-v.w));
    __builtin_nontemporal_store(o, reinterpret_cast<f4v*>(h + (size_t)n * HID + c * 4));
}

extern "C" void kernel_launch(void* const* d_in, const int* in_sizes, int n_in,
                              void* d_out, int out_size, void* d_ws, size_t ws_size,
                              hipStream_t stream) {
    const int* x = (const int*)d_in[0];
    const float* pos = (const float*)d_in[1];
    const int* eidx = (const int*)d_in[2];
    const float* emb = (const float*)d_in[3];

    const int N = in_sizes[0];
    const int E = in_sizes[2] / 2;
    const int* ei = eidx;
    const int* ej = eidx + E;

    float* out = (float*)d_out;
    float* out_h = out;
    float* out_dist = out + (size_t)N * HID;
    float* out_theta = out_dist + E;
    float* out_phi = out_theta + E;
    float* out_tau = out_phi + E;

    // scratch in h-region of d_out (102.4MB); k_embed runs last.
    ull* slotsA = (ull*)out_h;                    // 2N (interleaved min/2nd-min)
    ull* slotsB = slotsA + 2 * (size_t)N;         // 2N
    unsigned* thrA = (unsigned*)(slotsB + 2 * (size_t)N);   // N (clean snapshots)
    unsigned* thrB = thrA + N;                    // N
    float4* nodeI = (float4*)(thrB + N);          // 2N (paired A-side recs)
    float4* nodeJ = nodeI + 2 * (size_t)N;        // 2N
    float* vecs = (float*)(nodeJ + 2 * (size_t)N); // 3E
    int* a0i = (int*)(vecs + 3 * (size_t)E);      // N
    int* a0j = a0i + N;                           // N
    unsigned* flags = (unsigned*)(a0j + N);       // 2

    const int BS = 256;
    int gN = (N + BS - 1) / BS;
    int total4 = N * (HID / 4);
    int gH = (total4 + BS - 1) / BS;

    // init: 0xFF fill covers slotsA/slotsB sentinels AND thrA/thrB (=UINT_MAX,
    // pass-all for chunk 1); flags zeroed.
    (void)hipMemsetAsync(slotsA, 0xFF, 4 * (size_t)N * sizeof(ull) + 2 * (size_t)N * sizeof(unsigned), stream);
    (void)hipMemsetAsync(flags, 0, 2 * sizeof(unsigned), stream);

    // geometric chunks: 1/8, 1/8, 1/4, rest; snapshot between chunks
    int bounds[5] = {0, E / 8, E / 4, E / 2, E};
    for (int k = 0; k < 4; k++) {
        int lo = bounds[k], hi = bounds[k + 1];
        if (hi <= lo) continue;
        int g = (hi - lo + BS - 1) / BS;
        k_pass1<<<g, BS, 0, stream>>>(ei, ej, pos, out_dist, vecs, slotsA, slotsB,
                                      thrA, thrB, lo, hi);
        if (k < 3)
            k_snapshot<<<gN, BS, 0, stream>>>(slotsA, slotsB, thrA, thrB, N);
    }

    k_prep<<<gN, BS, 0, stream>>>(slotsA, slotsB, ei, ej, vecs,
                                  nodeI, nodeJ, a0i, a0j, flags, N);
    k_fix<<<2, BS, 0, stream>>>(flags, ei, ej, out_dist, a0i, a0j, vecs,
                                nodeI, nodeJ, E);
    k_angles<<<(E + BS - 1) / BS, BS, 0, stream>>>(ei, ej, vecs, out_dist, nodeI, nodeJ,
                                                   out_theta, out_phi, out_tau, E);
    k_embed<<<gH, BS, 0, stream>>>(x, emb, out_h, total4);
}

// Round 28
// 354.177 us; speedup vs baseline: 1.0338x; 1.0338x over previous
//
#include <hip/hip_runtime.h>
#include <math.h>

#define HID 256
#define PI_F 3.14159265358979323846f
typedef unsigned long long ull;
typedef float f4v __attribute__((ext_vector_type(4)));

struct F3 { float x, y, z; };

// ---- LOCKED NUMERICS (passing recipe, R14): clean dist (no FMA, numpy order,
// CR sqrt) + contracted crosses (fma(a.y,b.z,-(a.z*b.y))) + clean dots ----
__device__ __forceinline__ F3 crossc(F3 a, F3 b) {
    F3 r;
    float t1 = a.z * b.y;
    r.x = __builtin_fmaf(a.y, b.z, -t1);
    float t2 = a.x * b.z;
    r.y = __builtin_fmaf(a.z, b.x, -t2);
    float t3 = a.y * b.x;
    r.z = __builtin_fmaf(a.x, b.y, -t3);
    return r;
}
__device__ __forceinline__ float dotf(F3 a, F3 b) {
#pragma clang fp contract(off)
    float px = a.x * b.x;
    float py = a.y * b.y;
    float pz = a.z * b.z;
    return (px + py) + pz;
}
__device__ __forceinline__ float sqrt_cr(float ss) {
    return (float)sqrt((double)ss);
}
__device__ __forceinline__ float safe_atan2(float b, float a) {
    float aa = (a == 0.f && b == 0.f) ? 1.f : a;
    return atan2f(b, aa);
}
__device__ __forceinline__ F3 loadp(const float* __restrict__ pos, int n) {
    F3 r;
    r.x = pos[3 * n + 0];
    r.y = pos[3 * n + 1];
    r.z = pos[3 * n + 2];
    return r;
}
__device__ __forceinline__ F3 loadv(const float* __restrict__ vecs, int e) {
    F3 r;
    r.x = vecs[3 * (size_t)e + 0];
    r.y = vecs[3 * (size_t)e + 1];
    r.z = vecs[3 * (size_t)e + 2];
    return r;
}
__device__ __forceinline__ F3 subv(F3 a, F3 b) {
#pragma clang fp contract(off)
    F3 r;
    r.x = a.x - b.x;
    r.y = a.y - b.y;
    r.z = a.z - b.z;
    return r;
}
__device__ __forceinline__ ull umin64(ull a, ull b) { return a < b ? a : b; }
__device__ __forceinline__ ull umax64(ull a, ull b) { return a > b ? a : b; }

// two-slot lex-min insert, slots interleaved (s[0]=min, s[1]=2nd-min).
// Stale-safe filter: hi words monotone non-increasing; stale >= current.
// Invariant: every key not ending in s[0] is offered to s[1] at least once.
__device__ __forceinline__ void insert2(ull* __restrict__ s, unsigned db, ull key) {
    unsigned hi2 = ((const unsigned*)s)[3];
    if (db > hi2) return;
    unsigned hi1 = ((const unsigned*)s)[1];
    if (db <= hi1) {
        ull ret = atomicMin(&s[0], key);
        ull loser = umax64(ret, key);
        if (loser != ~0ull) atomicMin(&s[1], loser);
    } else {
        atomicMin(&s[1], key);
    }
}

__device__ __forceinline__ void pass1_body(const int* __restrict__ ei,
                                           const int* __restrict__ ej,
                                           const float* __restrict__ pos,
                                           float* __restrict__ dist,
                                           float* __restrict__ vecs,
                                           ull* __restrict__ slotsA,
                                           ull* __restrict__ slotsB,
                                           const unsigned* __restrict__ thrA,
                                           const unsigned* __restrict__ thrB,
                                           int e) {
#pragma clang fp contract(off)
    int ii = ei[e], jj = ej[e];
    F3 v = subv(loadp(pos, jj), loadp(pos, ii));
    vecs[3 * (size_t)e + 0] = v.x;
    vecs[3 * (size_t)e + 1] = v.y;
    vecs[3 * (size_t)e + 2] = v.z;
    float sx = v.x * v.x;
    float sy = v.y * v.y;
    float sz = v.z * v.z;
    float ss = (sx + sy) + sz;
    float d = (ss == 0.f) ? 0.f : sqrt_cr(ss);
    dist[e] = d;
    unsigned db = __float_as_uint(d);
    ull key = ((ull)db << 32) | (unsigned)e;
    if (db <= thrA[ii]) insert2(&slotsA[2 * (size_t)ii], db, key);
    if (db <= thrB[jj]) insert2(&slotsB[2 * (size_t)jj], db, key);
}

// ---------------- pass1 chunk ----------------
__global__ void k_pass1(const int* __restrict__ ei, const int* __restrict__ ej,
                        const float* __restrict__ pos, float* __restrict__ dist,
                        float* __restrict__ vecs,
                        ull* __restrict__ slotsA, ull* __restrict__ slotsB,
                        const unsigned* __restrict__ thrA, const unsigned* __restrict__ thrB,
                        int e0, int e1) {
    int e = e0 + blockIdx.x * blockDim.x + threadIdx.x;
    if (e >= e1) return;
    pass1_body(ei, ej, pos, dist, vecs, slotsA, slotsB, thrA, thrB, e);
}

// ---------------- final pass1 chunk FUSED with embed ----------------
// Edge blocks are latency-bound (filter->atomic chains) at ~15% HBM; embed
// blocks are pure streaming -> they soak the idle bandwidth concurrently.
__global__ void k_pass1_embed(const int* __restrict__ ei, const int* __restrict__ ej,
                              const float* __restrict__ pos, float* __restrict__ dist,
                              float* __restrict__ vecs,
                              ull* __restrict__ slotsA, ull* __restrict__ slotsB,
                              const unsigned* __restrict__ thrA, const unsigned* __restrict__ thrB,
                              int e0, int e1, int gEc,
                              const int* __restrict__ x, const float* __restrict__ w,
                              float* __restrict__ h, int total4) {
    if ((int)blockIdx.x < gEc) {
        int e = e0 + blockIdx.x * blockDim.x + threadIdx.x;
        if (e >= e1) return;
        pass1_body(ei, ej, pos, dist, vecs, slotsA, slotsB, thrA, thrB, e);
    } else {
        int t = ((int)blockIdx.x - gEc) * blockDim.x + threadIdx.x;
        if (t >= total4) return;
        int n = t >> 6;
        int c = t & 63;
        int row = x[n];
        float4 v = *reinterpret_cast<const float4*>(w + (size_t)row * HID + c * 4);
        f4v o;
        o.x = v.x / (1.f + expf(-v.x));
        o.y = v.y / (1.f + expf(-v.y));
        o.z = v.z / (1.f + expf(-v.z));
        o.w = v.w / (1.f + expf(-v.w));
        __builtin_nontemporal_store(o, reinterpret_cast<f4v*>(h + (size_t)n * HID + c * 4));
    }
}

// ---------------- snapshot: publish current 2nd-min dist-bits as clean thresholds ----------------
__global__ void k_snapshot(const ull* __restrict__ slotsA, const ull* __restrict__ slotsB,
                           unsigned* __restrict__ thrA, unsigned* __restrict__ thrB, int N) {
    int n = blockIdx.x * blockDim.x + threadIdx.x;
    if (n >= N) return;
    thrA[n] = (unsigned)(slotsA[2 * (size_t)n + 1] >> 32);
    thrB[n] = (unsigned)(slotsB[2 * (size_t)n + 1] >> 32);
}

// ---------------- prep: a0/a1 from top-2 + PAIRED node records (via vecs) ----------------
// argmin1 = lex-min( (bits(d0+8), a0), slot2 ) — bit-exact vs ref's dist+8 marking.
__global__ void k_prep(const ull* __restrict__ slotsA, const ull* __restrict__ slotsB,
                       const int* __restrict__ ei, const int* __restrict__ ej,
                       const float* __restrict__ vecs,
                       float4* __restrict__ nodeI, float4* __restrict__ nodeJ,
                       int* __restrict__ a0i, int* __restrict__ a0j,
                       unsigned* __restrict__ flags, int N) {
#pragma clang fp contract(off)
    int n = blockIdx.x * blockDim.x + threadIdx.x;
    if (n >= N) return;

    // A side
    ull k1 = slotsA[2 * (size_t)n];
    int a0, a1;
    if (k1 == ~0ull) {
        a0 = 0; a1 = 0;
        atomicOr(&flags[0], 1u);
    } else {
        a0 = (int)(k1 & 0xffffffffu);
        float d0 = __uint_as_float((unsigned)(k1 >> 32));
        ull mkey = ((ull)__float_as_uint(d0 + 8.0f) << 32) | (unsigned)a0;
        ull k2 = slotsA[2 * (size_t)n + 1];
        if (k2 == ~0ull) a1 = a0;                       // 1-edge segment
        else a1 = (mkey < k2) ? a0 : (int)(k2 & 0xffffffffu);
    }
    a0i[n] = a0;
    F3 in0 = loadv(vecs, a0);
    int n0 = ej[a0];
    F3 in1 = loadv(vecs, a1);
    nodeI[2 * (size_t)n]     = make_float4(in0.x, in0.y, in0.z, __int_as_float(n0));
    nodeI[2 * (size_t)n + 1] = make_float4(in1.x, in1.y, in1.z, 0.f);

    // B side
    ull q1 = slotsB[2 * (size_t)n];
    int b0, b1;
    if (q1 == ~0ull) {
        b0 = 0; b1 = 0;
        atomicOr(&flags[1], 1u);
    } else {
        b0 = (int)(q1 & 0xffffffffu);
        float d0 = __uint_as_float((unsigned)(q1 >> 32));
        ull mkey = ((ull)__float_as_uint(d0 + 8.0f) << 32) | (unsigned)b0;
        ull q2 = slotsB[2 * (size_t)n + 1];
        if (q2 == ~0ull) b1 = b0;
        else b1 = (mkey < q2) ? b0 : (int)(q2 & 0xffffffffu);
    }
    a0j[n] = b0;
    F3 w0 = loadv(vecs, b0);
    int m0 = ei[b0];
    F3 w1 = loadv(vecs, b1);
    nodeJ[2 * (size_t)n]     = make_float4(w0.x, w0.y, w0.z, __int_as_float(m0));
    nodeJ[2 * (size_t)n + 1] = make_float4(w1.x, w1.y, w1.z, 0.f);
}

// ---------------- fix: exact edge-0 marking when some segment is empty ----------------
// (never fires on this data; exact ref semantics if it does)
__global__ void k_fix(const unsigned* __restrict__ flags,
                      const int* __restrict__ ei, const int* __restrict__ ej,
                      const float* __restrict__ dist,
                      const int* __restrict__ a0i, const int* __restrict__ a0j,
                      const float* __restrict__ vecs,
                      float4* __restrict__ nodeI, float4* __restrict__ nodeJ, int E) {
#pragma clang fp contract(off)
    __shared__ ull smin[256];
    int side = blockIdx.x;          // 0 = A, 1 = B
    if (flags[side] == 0u) return;
    const int* seg = (side == 0) ? ei : ej;
    int s = seg[0];
    int marked = (side == 0) ? a0i[s] : a0j[s];
    ull local = ~0ull;
    for (int e = threadIdx.x; e < E; e += 256) {
        if (seg[e] != s) continue;
        float d = dist[e];
        float dm = (e == marked || e == 0) ? (d + 8.0f) : d;
        ull key = ((ull)__float_as_uint(dm) << 32) | (unsigned)e;
        local = umin64(local, key);
    }
    smin[threadIdx.x] = local;
    __syncthreads();
    for (int w = 128; w > 0; w >>= 1) {
        if (threadIdx.x < w) smin[threadIdx.x] = umin64(smin[threadIdx.x], smin[threadIdx.x + w]);
        __syncthreads();
    }
    if (threadIdx.x == 0) {
        int a1 = (smin[0] == ~0ull) ? 0 : (int)(smin[0] & 0xffffffffu);
        F3 v = loadv(vecs, a1);
        if (side == 0) nodeI[2 * (size_t)s + 1] = make_float4(v.x, v.y, v.z, 0.f);
        else           nodeJ[2 * (size_t)s + 1] = make_float4(v.x, v.y, v.z, 0.f);
    }
}

// ---------------- angles: streaming vecs + 2 paired-line gathers ----------------
__global__ void k_angles(const int* __restrict__ ei, const int* __restrict__ ej,
                         const float* __restrict__ vecs, const float* __restrict__ dist,
                         const float4* __restrict__ nodeI, const float4* __restrict__ nodeJ,
                         float* __restrict__ theta, float* __restrict__ phi,
                         float* __restrict__ tau, int E) {
    int e = blockIdx.x * blockDim.x + threadIdx.x;
    if (e >= E) return;
    int ii = ei[e], jj = ej[e];

    float4 A0 = nodeI[2 * (size_t)ii];
    float4 A1 = nodeI[2 * (size_t)ii + 1];
    float4 B0 = nodeJ[2 * (size_t)jj];
    float4 B1 = nodeJ[2 * (size_t)jj + 1];
    int n0 = __float_as_int(A0.w);
    int m0 = __float_as_int(B0.w);

    F3 in0; in0.x = A0.x; in0.y = A0.y; in0.z = A0.z;
    F3 in1; in1.x = A1.x; in1.y = A1.y; in1.z = A1.z;
    F3 w0;  w0.x = B0.x;  w0.y = B0.y;  w0.z = B0.z;
    F3 w1;  w1.x = B1.x;  w1.y = B1.y;  w1.z = B1.z;

    F3 iref = (n0 == jj) ? in1 : in0;
    F3 jref = (m0 == ii) ? w1 : w0;

    // p read STREAMING from vecs (bitwise == subv(pos[jj],pos[ii]) in pass1)
    F3 p = loadv(vecs, e);
    F3 mp;
    mp.x = -p.x; mp.y = -p.y; mp.z = -p.z;

    // theta
    float a = dotf(mp, in0);
    F3 c1 = crossc(mp, in0);
    float ssb = dotf(c1, c1);
    float b = (ssb == 0.f) ? 0.f : sqrt_cr(ssb);
    float th = safe_atan2(b, a);
    if (th < 0.f) th += PI_F;

    float dji = dist[e];

    // phi
    F3 pl2 = crossc(mp, in1);
    a = dotf(c1, pl2);
    F3 cc = crossc(c1, pl2);
    b = dotf(cc, p) / dji;
    float ph = safe_atan2(b, a);
    if (ph < 0.f) ph += PI_F;

    // tau
    F3 t1 = crossc(p, jref);
    F3 t2 = crossc(p, iref);
    a = dotf(t1, t2);
    cc = crossc(t1, t2);
    b = dotf(cc, p) / dji;
    float ta = safe_atan2(b, a);
    if (ta < 0.f) ta += PI_F;

    // outputs never re-read: nontemporal (keep L2 for node-record gathers)
    __builtin_nontemporal_store(th, &theta[e]);
    __builtin_nontemporal_store(ph, &phi[e]);
    __builtin_nontemporal_store(ta, &tau[e]);
}

extern "C" void kernel_launch(void* const* d_in, const int* in_sizes, int n_in,
                              void* d_out, int out_size, void* d_ws, size_t ws_size,
                              hipStream_t stream) {
    const int* x = (const int*)d_in[0];
    const float* pos = (const float*)d_in[1];
    const int* eidx = (const int*)d_in[2];
    const float* emb = (const float*)d_in[3];

    const int N = in_sizes[0];
    const int E = in_sizes[2] / 2;
    const int* ei = eidx;
    const int* ej = eidx + E;

    float* out = (float*)d_out;
    float* out_h = out;
    float* out_dist = out + (size_t)N * HID;
    float* out_theta = out_dist + E;
    float* out_phi = out_theta + E;
    float* out_tau = out_phi + E;

    // ALL scratch in d_ws (~50MB used; ws_size ≈ 4x out bytes ≈ 600MB).
    // h is a pure output now -> embed can be fused into pass1 (overlap).
    char* ws = (char*)d_ws;
    ull* slotsA = (ull*)ws;                       // 2N (interleaved min/2nd-min)
    ull* slotsB = slotsA + 2 * (size_t)N;         // 2N
    unsigned* thrA = (unsigned*)(slotsB + 2 * (size_t)N);   // N (clean snapshots)
    unsigned* thrB = thrA + N;                    // N
    float4* nodeI = (float4*)(thrB + N);          // 2N (paired A-side recs)
    float4* nodeJ = nodeI + 2 * (size_t)N;        // 2N
    float* vecs = (float*)(nodeJ + 2 * (size_t)N); // 3E
    int* a0i = (int*)(vecs + 3 * (size_t)E);      // N
    int* a0j = a0i + N;                           // N
    unsigned* flags = (unsigned*)(a0j + N);       // 2

    const int BS = 256;
    int gN = (N + BS - 1) / BS;
    int total4 = N * (HID / 4);
    int gH = (total4 + BS - 1) / BS;

    // init: 0xFF fill covers slots sentinels AND thr (=UINT_MAX pass-all); flags zeroed
    (void)hipMemsetAsync(slotsA, 0xFF, 4 * (size_t)N * sizeof(ull) + 2 * (size_t)N * sizeof(unsigned), stream);
    (void)hipMemsetAsync(flags, 0, 2 * sizeof(unsigned), stream);

    // geometric chunks: 1/16, 1/16, 1/8, 1/4, rest; snapshot between chunks.
    // Final (largest) chunk is fused with embed: its edge blocks are
    // latency-bound, embed's streaming soaks the idle bandwidth.
    int bounds[6] = {0, E / 16, E / 8, E / 4, E / 2, E};
    for (int k = 0; k < 4; k++) {
        int lo = bounds[k], hi = bounds[k + 1];
        if (hi <= lo) continue;
        int g = (hi - lo + BS - 1) / BS;
        k_pass1<<<g, BS, 0, stream>>>(ei, ej, pos, out_dist, vecs, slotsA, slotsB,
                                      thrA, thrB, lo, hi);
        k_snapshot<<<gN, BS, 0, stream>>>(slotsA, slotsB, thrA, thrB, N);
    }
    {
        int lo = bounds[4], hi = bounds[5];
        int gEc = (hi - lo + BS - 1) / BS;
        k_pass1_embed<<<gEc + gH, BS, 0, stream>>>(ei, ej, pos, out_dist, vecs,
                                                   slotsA, slotsB, thrA, thrB,
                                                   lo, hi, gEc, x, emb, out_h, total4);
    }

    k_prep<<<gN, BS, 0, stream>>>(slotsA, slotsB, ei, ej, vecs,
                                  nodeI, nodeJ, a0i, a0j, flags, N);
    k_fix<<<2, BS, 0, stream>>>(flags, ei, ej, out_dist, a0i, a0j, vecs,
                                nodeI, nodeJ, E);
    k_angles<<<(E + BS - 1) / BS, BS, 0, stream>>>(ei, ej, vecs, out_dist, nodeI, nodeJ,
                                                   out_theta, out_phi, out_tau, E);
}